// Round 2
// baseline (1385.446 us; speedup 1.0000x reference)
//
#include <hip/hip_runtime.h>
#include <cstdint>
#include <cstddef>

// ---------------------------------------------------------------------------
// HAN forward on gfx950. Float input dtype (fp32 vs bf16) unknown at build
// time -> probe kernel writes mode flag; prep kernels convert all hot-path
// operands to bf16/fp16 once (Whh swizzled into MFMA-fragment order for the
// 8-wave GRU). GRU: 512-thread blocks, h fp32 in registers + hi/lo bf16 LDS
// mirrors (double-buffered, 1 barrier/step), B half-persisted in registers
// (groups 0..2) + half streamed from L2 (groups 3..5), K split in 2 phases.
// enc stored fp16 (|h|<=1) and sentence-phase buffers alias the word-phase
// region so nb=640 fits -> single 80-block word GRU dispatch (2x CUs).
// ---------------------------------------------------------------------------

typedef __attribute__((ext_vector_type(8))) short bf16x8;   // 8 bf16 = 4 VGPR
typedef __attribute__((ext_vector_type(8))) _Float16 f16x8; // 8 fp16 = 4 VGPR
typedef __attribute__((ext_vector_type(4))) float f32x4;

__device__ __forceinline__ float bfraw2f(unsigned int u16) {
    unsigned int x = u16 << 16; float f; __builtin_memcpy(&f, &x, 4); return f;
}
__device__ __forceinline__ unsigned short f2bfraw(float f) {  // RNE
    unsigned int u; __builtin_memcpy(&u, &f, 4);
    unsigned int r = u + 0x7fffu + ((u >> 16) & 1u);
    return (unsigned short)(r >> 16);
}
__device__ __forceinline__ unsigned short f2h(float f) {
    _Float16 h = (_Float16)f; unsigned short u; __builtin_memcpy(&u, &h, 2); return u;
}
__device__ __forceinline__ float h2f(unsigned short u) {
    _Float16 h; __builtin_memcpy(&h, &u, 2); return (float)h;
}
__device__ __forceinline__ float bflo(unsigned int p) {
    unsigned int x = p << 16; float f; __builtin_memcpy(&f, &x, 4); return f;
}
__device__ __forceinline__ float bfhi(unsigned int p) {
    unsigned int x = p & 0xffff0000u; float f; __builtin_memcpy(&f, &x, 4); return f;
}
__device__ __forceinline__ float fast_sigmoid(float x) { return 1.f / (1.f + __expf(-x)); }
__device__ __forceinline__ float fast_tanh(float x) {
    x = fminf(fmaxf(x, -30.f), 30.f);
    float e = __expf(2.f * x);
    return (e - 1.f) / (e + 1.f);
}
__device__ __forceinline__ float fin(float x) {
    return (x == x && fabsf(x) < 1e30f) ? x : 0.f;
}

// ---- dual-mode input adapters (m=1: bf16 u16 buffer, m=0: fp32 buffer) ----
__device__ __forceinline__ float ldsc(const void* p, size_t i, int m) {
    return m ? bfraw2f(((const unsigned short*)p)[i]) : ((const float*)p)[i];
}
__device__ __forceinline__ bf16x8 ld8bf(const void* p, size_t ei, int m) {
    if (m) return *(const bf16x8*)((const unsigned short*)p + ei);
    const float* f = (const float*)p + ei;
    f32x4 a = *(const f32x4*)f, b = *(const f32x4*)(f + 4);
    bf16x8 r;
    r[0] = (short)f2bfraw(a[0]); r[1] = (short)f2bfraw(a[1]);
    r[2] = (short)f2bfraw(a[2]); r[3] = (short)f2bfraw(a[3]);
    r[4] = (short)f2bfraw(b[0]); r[5] = (short)f2bfraw(b[1]);
    r[6] = (short)f2bfraw(b[2]); r[7] = (short)f2bfraw(b[3]);
    return r;
}
__device__ __forceinline__ void ld8f(const void* p, size_t ei, int m, float* o) {
    if (m) {
        uint4 wv = *(const uint4*)((const unsigned short*)p + ei);
        o[0] = bflo(wv.x); o[1] = bfhi(wv.x); o[2] = bflo(wv.y); o[3] = bfhi(wv.y);
        o[4] = bflo(wv.z); o[5] = bfhi(wv.z); o[6] = bflo(wv.w); o[7] = bfhi(wv.w);
    } else {
        const float* f = (const float*)p + ei;
        #pragma unroll
        for (int i = 0; i < 8; ++i) o[i] = f[i];
    }
}

// ---------------------------------------------------------------------------
// K0: dtype probe. flag[0] = mode (1=bf16, 0=fp32); flag[1] = 1 always.
// ---------------------------------------------------------------------------
__global__ void k_probe(const unsigned short* __restrict__ w, int* __restrict__ flag) {
    if (threadIdx.x == 0) {
        int bad = 0;
        for (int i = 0; i < 512; ++i) {
            float v = bfraw2f(w[i]);
            if (!(fabsf(v) <= 1.0f)) bad++;
        }
        flag[0] = (bad == 0) ? 1 : 0;
        flag[1] = 1;
    }
}

// ---------------------------------------------------------------------------
// P1a: generic dual-mode -> bf16 convert.  P1b: -> fp16 convert.
// ---------------------------------------------------------------------------
__global__ void p_cvt(const void* __restrict__ src, unsigned short* __restrict__ dst,
                      int n, const int* __restrict__ modep) {
    const int m = modep[0];
    for (int i = blockIdx.x * 256 + threadIdx.x; i < n; i += gridDim.x * 256)
        dst[i] = f2bfraw(ldsc(src, i, m));
}
__global__ void p_cvt_h(const void* __restrict__ src, unsigned short* __restrict__ dst,
                        int n, const int* __restrict__ modep) {
    const int m = modep[0];
    for (int i = blockIdx.x * 256 + threadIdx.x; i < n; i += gridDim.x * 256)
        dst[i] = f2h(ldsc(src, i, m));
}

// ---------------------------------------------------------------------------
// P2: Whh (768x256) -> bf16 MFMA-fragment order for the 8-wave GRU.
// wave w owns hidden cols [w*32, w*32+32): groups g = reg*2+nt (reg=gate,
// nt=col-tile). Fragment f = (w*6+g)*8+ks, elem addr = f*512 + lane*8 + e.
// Source = whh[(reg*256 + w*32 + nt*16 + lm)*256 + ks*32 + q*8 + e].
// ---------------------------------------------------------------------------
__global__ void p_whh_swz(const void* __restrict__ whh, unsigned short* __restrict__ dst,
                          const int* __restrict__ modep) {
    const int m = modep[0];
    const int idx = blockIdx.x * 256 + threadIdx.x;    // 24576 = 8*6*8*64
    if (idx >= 24576) return;
    const int lane = idx & 63, ks = (idx >> 6) & 7;
    const int g = (idx >> 9) % 6, w = idx / 3072;
    const int lm = lane & 15, q = lane >> 4;
    const int reg = g >> 1, nt = g & 1;
    const int row = reg * 256 + w * 32 + nt * 16 + lm;
    const size_t src = (size_t)row * 256 + ks * 32 + q * 8;
    const size_t d = (size_t)idx * 8;
    #pragma unroll
    for (int e = 0; e < 8; ++e) dst[d + e] = f2bfraw(ldsc(whh, src + e, m));
}

// ---------------------------------------------------------------------------
// K1: gathered word projection. xp[dir][t*nb+bl][768] fp16. grid (nb, 6).
// ---------------------------------------------------------------------------
__global__ __launch_bounds__(256, 2) void k_xp_word(
    const void* __restrict__ embA, const int* __restrict__ batch_doc,
    const unsigned short* __restrict__ wih,       // bf16 [1536][512]
    const void* __restrict__ bih_f, const void* __restrict__ bih_b,
    unsigned short* __restrict__ xp, int b0, int nb,
    const int* __restrict__ amode, const int* __restrict__ modep)
{
    __shared__ unsigned short As[64][40];
    __shared__ unsigned short Bs[256][40];
    const int am = amode[0], m = modep[0];
    const int bm = blockIdx.x, bc = blockIdx.y;
    const int tid = threadIdx.x;
    const int wave = tid >> 6, lane = tid & 63, lm = lane & 15, q = lane >> 4;
    const int arow = tid >> 2, akoff = (tid & 3) * 8;
    const int r = bm * 64 + arow;
    const int tt = r / nb, bl = r - tt * nb;
    const size_t aei = (size_t)batch_doc[(b0 + bl) * 64 + tt] * 512 + akoff;

    const f32x4 fzero = {0.f, 0.f, 0.f, 0.f};
    f32x4 acc[4][4];
    #pragma unroll
    for (int i = 0; i < 4; ++i)
        #pragma unroll
        for (int j = 0; j < 4; ++j) acc[i][j] = fzero;

    for (int kt = 0; kt < 16; ++kt) {
        *(bf16x8*)&As[arow][akoff] = ld8bf(embA, aei + kt * 32, am);
        #pragma unroll
        for (int ld = 0; ld < 4; ++ld) {
            int e = ld * 256 + tid;
            int n = e >> 2, koff = (e & 3) * 8;
            int gn = bc * 256 + n;
            *(uint4*)&Bs[n][koff] = *(const uint4*)(wih + (size_t)gn * 512 + kt * 32 + koff);
        }
        __syncthreads();
        bf16x8 af[4], bv[4];
        #pragma unroll
        for (int mt = 0; mt < 4; ++mt) af[mt] = *(const bf16x8*)&As[mt * 16 + lm][q * 8];
        #pragma unroll
        for (int nt = 0; nt < 4; ++nt) bv[nt] = *(const bf16x8*)&Bs[wave * 64 + nt * 16 + lm][q * 8];
        #pragma unroll
        for (int mt = 0; mt < 4; ++mt)
            #pragma unroll
            for (int nt = 0; nt < 4; ++nt)
                acc[mt][nt] = __builtin_amdgcn_mfma_f32_16x16x32_bf16(af[mt], bv[nt], acc[mt][nt], 0, 0, 0);
        __syncthreads();
    }

    const size_t XPT = (size_t)64 * nb * 768;
    #pragma unroll
    for (int nt = 0; nt < 4; ++nt) {
        const int cn = bc * 256 + wave * 64 + nt * 16 + lm;
        const int dirb = (cn >= 768);
        const int o = cn - dirb * 768;
        const float bias = ldsc(dirb ? bih_b : bih_f, o, m);
        #pragma unroll
        for (int mt = 0; mt < 4; ++mt)
            #pragma unroll
            for (int j = 0; j < 4; ++j) {
                const int rr = bm * 64 + mt * 16 + q * 4 + j;
                xp[(dirb ? XPT : 0) + (size_t)rr * 768 + o] = f2h(acc[mt][nt][j] + bias);
            }
    }
}

// ---------------------------------------------------------------------------
// K2: pipelined GRU. 512 threads (8 waves, 2/SIMD). Wave w owns hidden cols
// [w*32, w*32+32). h fp32 in REGISTERS (lane owns its (s,col) elements);
// hi/lo bf16 mirrors + xp tile in double-buffered LDS -> 1 barrier/step.
// B (swizzled bf16): groups 0..2 persisted in VGPRs/AGPRs, groups 3..5
// streamed from L2 each step; K split in 2 phases (ks 0-3 / 4-7).
// grid = 2*(NB/16), dir = blockIdx&1. xp fp16 [dir][T*NB][768].
// enc written fp16 (|h| <= 1).
// ---------------------------------------------------------------------------
__global__ __launch_bounds__(512, 2) void k_gru(
    const unsigned short* __restrict__ xp,
    const unsigned short* __restrict__ wswz_f,      // bf16 swizzled 196608
    const unsigned short* __restrict__ wswz_b,
    const void* __restrict__ bhh_f, const void* __restrict__ bhh_b,
    const int* __restrict__ lens, unsigned short* __restrict__ enc, int T, int NB,
    const int* __restrict__ modep)
{
    __shared__ unsigned short hHi[2][16][264];   // pitch 528B
    __shared__ unsigned short hLo[2][16][264];
    __shared__ unsigned short xpS[2][16][776];   // fp16, pitch 1552B
    __shared__ float bhhS[768];
    __shared__ int lensS[16];
    const int m = modep[0];
    const int tid = threadIdx.x;
    const int w = tid >> 6, lane = tid & 63, lm = lane & 15, q = lane >> 4;
    const int dir = blockIdx.x & 1, sg = blockIdx.x >> 1;
    const int s0 = sg << 4;
    const unsigned short* wsw =
        (dir ? wswz_b : wswz_f) + (size_t)w * 24576 + (size_t)lane * 8;
    const void* bhh = dir ? bhh_b : bhh_f;
    const unsigned short* xpd = xp + (dir ? (size_t)T * NB * 768 : 0);

    for (int e = tid; e < 16 * 264; e += 512) {
        (&hHi[0][0][0])[e] = 0; (&hLo[0][0][0])[e] = 0;
    }
    for (int j = tid; j < 768; j += 512) bhhS[j] = ldsc(bhh, j, m);
    if (tid < 16) lensS[tid] = lens[s0 + tid];

    // persistent B: groups 0..2 (24 fragments = 96 regs), loaded once.
    bf16x8 bper[3][8];
    #pragma unroll
    for (int g = 0; g < 3; ++g)
        #pragma unroll
        for (int ks = 0; ks < 8; ++ks)
            bper[g][ks] = *(const bf16x8*)(wsw + (size_t)(g * 8 + ks) * 512);

    // prologue: stage xp(t0) into xpS[0]
    {
        const int t0 = dir ? (T - 1) : 0;
        const unsigned short* xrow = xpd + ((size_t)t0 * NB + s0) * 768;
        #pragma unroll
        for (int i = 0; i < 3; ++i) {
            int e = tid + i * 512;                 // [0,1536) dwordx4 slots
            uint4 v = *(const uint4*)(xrow + e * 8);
            *(uint4*)&xpS[0][e / 96][(e % 96) * 8] = v;
        }
    }
    __syncthreads();

    const f32x4 fzero = {0.f, 0.f, 0.f, 0.f};
    float hreg[2][4] = {};                         // h fp32, lane-owned
    uint4 stg[3];
    for (int step = 0; step < T; ++step) {
        const int t = dir ? (T - 1 - step) : step;
        const int cur = step & 1, nxt = cur ^ 1;

        // prefetch next step's xp tile into registers (overlaps everything)
        const bool havenext = (step + 1 < T);
        if (havenext) {
            const int tn = dir ? (T - 2 - step) : (step + 1);
            const unsigned short* xrow = xpd + ((size_t)tn * NB + s0) * 768;
            #pragma unroll
            for (int i = 0; i < 3; ++i)
                stg[i] = *(const uint4*)(xrow + (tid + i * 512) * 8);
        }

        f32x4 acc[6];
        #pragma unroll
        for (int i = 0; i < 6; ++i) acc[i] = fzero;

        // two K-phases: ks 0-3 then 4-7. Per phase: 8 A-frag ds_reads,
        // 12 streamed B loads (groups 3..5), 48 MFMAs (persisted first so
        // the streamed loads' L2 latency is covered).
        #pragma unroll
        for (int ph = 0; ph < 2; ++ph) {
            const int kb = ph * 4;
            bf16x8 ahi[4], alo[4];
            #pragma unroll
            for (int k = 0; k < 4; ++k) {
                ahi[k] = *(const bf16x8*)&hHi[cur][lm][(kb + k) * 32 + q * 8];
                alo[k] = *(const bf16x8*)&hLo[cur][lm][(kb + k) * 32 + q * 8];
            }
            bf16x8 bs3[4], bs4[4], bs5[4];
            #pragma unroll
            for (int k = 0; k < 4; ++k) {
                bs3[k] = *(const bf16x8*)(wsw + (size_t)(24 + kb + k) * 512);
                bs4[k] = *(const bf16x8*)(wsw + (size_t)(32 + kb + k) * 512);
                bs5[k] = *(const bf16x8*)(wsw + (size_t)(40 + kb + k) * 512);
            }
            #pragma unroll
            for (int g = 0; g < 3; ++g)
                #pragma unroll
                for (int k = 0; k < 4; ++k) {
                    acc[g] = __builtin_amdgcn_mfma_f32_16x16x32_bf16(ahi[k], bper[g][kb + k], acc[g], 0, 0, 0);
                    acc[g] = __builtin_amdgcn_mfma_f32_16x16x32_bf16(alo[k], bper[g][kb + k], acc[g], 0, 0, 0);
                }
            #pragma unroll
            for (int k = 0; k < 4; ++k) {
                acc[3] = __builtin_amdgcn_mfma_f32_16x16x32_bf16(ahi[k], bs3[k], acc[3], 0, 0, 0);
                acc[3] = __builtin_amdgcn_mfma_f32_16x16x32_bf16(alo[k], bs3[k], acc[3], 0, 0, 0);
                acc[4] = __builtin_amdgcn_mfma_f32_16x16x32_bf16(ahi[k], bs4[k], acc[4], 0, 0, 0);
                acc[4] = __builtin_amdgcn_mfma_f32_16x16x32_bf16(alo[k], bs4[k], acc[4], 0, 0, 0);
                acc[5] = __builtin_amdgcn_mfma_f32_16x16x32_bf16(ahi[k], bs5[k], acc[5], 0, 0, 0);
                acc[5] = __builtin_amdgcn_mfma_f32_16x16x32_bf16(alo[k], bs5[k], acc[5], 0, 0, 0);
            }
        }

        // gates: lane element (s=q*4+j, col=w*32+nt*16+lm), nt in {0,1}
        #pragma unroll
        for (int nt = 0; nt < 2; ++nt) {
            const int col = w * 32 + nt * 16 + lm;
            const float br = bhhS[col], bz = bhhS[256 + col], bn = bhhS[512 + col];
            #pragma unroll
            for (int j = 0; j < 4; ++j) {
                const int s = q * 4 + j;
                const float xr = h2f(xpS[cur][s][col]);
                const float xz = h2f(xpS[cur][s][256 + col]);
                const float xn = h2f(xpS[cur][s][512 + col]);
                const float rr = fast_sigmoid(xr + acc[nt][j] + br);
                const float zz = fast_sigmoid(xz + acc[2 + nt][j] + bz);
                const float nn = fast_tanh(xn + rr * (acc[4 + nt][j] + bn));
                const float hold = hreg[nt][j];
                float hnew = (1.f - zz) * nn + zz * hold;
                const bool v = (t < lensS[s]);
                hnew = v ? hnew : hold;
                hreg[nt][j] = hnew;
                const unsigned short uh = f2bfraw(hnew);
                hHi[nxt][s][col] = uh;
                hLo[nxt][s][col] = f2bfraw(hnew - bfraw2f(uh));
                enc[((size_t)t * NB + s0 + s) * 512 + (size_t)dir * 256 + col] = f2h(v ? hnew : 0.f);
            }
        }

        if (havenext) {    // write prefetched xp tile into the other buffer
            #pragma unroll
            for (int i = 0; i < 3; ++i) {
                int e = tid + i * 512;
                *(uint4*)&xpS[nxt][e / 96][(e % 96) * 8] = stg[i];
            }
        }
        __syncthreads();   // h[nxt] + xpS[nxt] visible for next step
    }
}

// ---------------------------------------------------------------------------
// K3: attention scores, GEMM (M x 512)@(512x512) + fused tanh*attw reduce.
// enc and lin are fp16 -> f16 MFMA (A needs no conversion at all).
// ---------------------------------------------------------------------------
__global__ __launch_bounds__(256, 1) void k_att(
    const unsigned short* __restrict__ enc,       // fp16 [M][512]
    const unsigned short* __restrict__ lin_w,     // fp16 [512][512]
    const void* __restrict__ lin_b, const void* __restrict__ attw,
    float* __restrict__ att_out, const int* __restrict__ modep)
{
    __shared__ unsigned short As[64][40];
    __shared__ unsigned short Bs[512][40];
    __shared__ float att_part[4][64];
    const int m = modep[0];
    const int bm = blockIdx.x;
    const int tid = threadIdx.x;
    const int wave = tid >> 6, lane = tid & 63, lm = lane & 15, q = lane >> 4;
    const int arow = tid >> 2, akoff = (tid & 3) * 8;
    const unsigned short* aptr = enc + (size_t)(bm * 64 + arow) * 512 + akoff;

    const f32x4 fzero = {0.f, 0.f, 0.f, 0.f};
    f32x4 acc[4][8];
    #pragma unroll
    for (int i = 0; i < 4; ++i)
        #pragma unroll
        for (int j = 0; j < 8; ++j) acc[i][j] = fzero;

    for (int kt = 0; kt < 16; ++kt) {
        *(uint4*)&As[arow][akoff] = *(const uint4*)(aptr + kt * 32);
        #pragma unroll
        for (int ld = 0; ld < 8; ++ld) {
            int e = ld * 256 + tid;
            int n = e >> 2, koff = (e & 3) * 8;
            *(uint4*)&Bs[n][koff] = *(const uint4*)(lin_w + (size_t)n * 512 + kt * 32 + koff);
        }
        __syncthreads();
        f16x8 af[4];
        #pragma unroll
        for (int mt = 0; mt < 4; ++mt) af[mt] = *(const f16x8*)&As[mt * 16 + lm][q * 8];
        #pragma unroll
        for (int nt = 0; nt < 8; ++nt) {
            f16x8 bv = *(const f16x8*)&Bs[wave * 128 + nt * 16 + lm][q * 8];
            #pragma unroll
            for (int mt = 0; mt < 4; ++mt)
                acc[mt][nt] = __builtin_amdgcn_mfma_f32_16x16x32_f16(af[mt], bv, acc[mt][nt], 0, 0, 0);
        }
        __syncthreads();
    }

    float part[4][4] = {};
    #pragma unroll
    for (int nt = 0; nt < 8; ++nt) {
        const int col = wave * 128 + nt * 16 + lm;
        const float lb = ldsc(lin_b, col, m);
        const float aw = ldsc(attw, col, m);
        #pragma unroll
        for (int mt = 0; mt < 4; ++mt)
            #pragma unroll
            for (int j = 0; j < 4; ++j)
                part[mt][j] += fast_tanh(acc[mt][nt][j] + lb) * aw;
    }
    #pragma unroll
    for (int mt = 0; mt < 4; ++mt)
        #pragma unroll
        for (int j = 0; j < 4; ++j) {
            float v = part[mt][j];
            #pragma unroll
            for (int d0 = 1; d0 < 16; d0 <<= 1) v += __shfl_xor(v, d0);
            part[mt][j] = v;
        }
    if (lm == 0) {
        #pragma unroll
        for (int mt = 0; mt < 4; ++mt)
            #pragma unroll
            for (int j = 0; j < 4; ++j)
                att_part[wave][mt * 16 + q * 4 + j] = part[mt][j];
    }
    __syncthreads();
    if (tid < 64)
        att_out[(size_t)bm * 64 + tid] =
            att_part[0][tid] + att_part[1][tid] + att_part[2][tid] + att_part[3][tid];
}

// ---------------------------------------------------------------------------
// K4: masked softmax over t + weighted sum of enc (fp16) rows. grid = NB.
// ---------------------------------------------------------------------------
__global__ __launch_bounds__(256) void k_softsum(
    const float* __restrict__ att, const unsigned short* __restrict__ enc,
    const int* __restrict__ lens, float* __restrict__ out,
    float* __restrict__ zero_row, int T, int NB)
{
    __shared__ float eS[64];
    __shared__ float dS;
    const int bb = blockIdx.x, tid = threadIdx.x;
    if (zero_row && bb == 0) { for (int j = tid; j < 512; j += 256) zero_row[j] = 0.f; }
    const int len = lens[bb];
    if (tid < T) {
        float a = fminf(att[(size_t)tid * NB + bb], 50.f);
        eS[tid] = (tid < len) ? __expf(a) : 0.f;
    }
    __syncthreads();
    if (tid == 0) { float s = 0.f; for (int t2 = 0; t2 < T; ++t2) s += eS[t2]; dS = s + 1e-4f; }
    __syncthreads();
    const float inv = 1.f / dS;
    for (int j = tid; j < 512; j += 256) {
        float a0 = 0.f;
        for (int t2 = 0; t2 < T; ++t2) a0 += eS[t2] * h2f(enc[((size_t)t2 * NB + bb) * 512 + j]);
        out[(size_t)bb * 512 + j] = fin(a0 * inv);
    }
}

// ---------------------------------------------------------------------------
// K5: sentence gather + sentence input projection; writes xp_s fp16.
// ---------------------------------------------------------------------------
__global__ __launch_bounds__(256) void k_sent_xp(
    const int* __restrict__ sent_order, const float* __restrict__ sent_pad,
    const unsigned short* __restrict__ swih,      // bf16 [1536][512]
    const void* __restrict__ bih_f, const void* __restrict__ bih_b,
    float* __restrict__ each_sent, unsigned short* __restrict__ xp_s,
    const int* __restrict__ modep)
{
    __shared__ float aS[512];
    const int m = modep[0];
    const int r = blockIdx.x, tid = threadIdx.x;
    const int idx = sent_order[r];
    const float* src = sent_pad + (size_t)idx * 512;
    for (int j = tid; j < 512; j += 256) { float v = src[j]; aS[j] = v; each_sent[(size_t)r * 512 + j] = v; }
    __syncthreads();
    const int d = r / 40, i2 = r % 40;
    #pragma unroll
    for (int p = 0; p < 6; ++p) {
        const int o = p * 256 + tid;
        const int dirb = (o >= 768);
        const int oo = o - dirb * 768;
        float s = ldsc(dirb ? bih_b : bih_f, oo, m);
        const unsigned short* wrow = swih + (size_t)o * 512;
        for (int k = 0; k < 512; k += 8) {
            const uint4 wv = *(const uint4*)(wrow + k);
            float wf[8];
            wf[0] = bflo(wv.x); wf[1] = bfhi(wv.x); wf[2] = bflo(wv.y); wf[3] = bfhi(wv.y);
            wf[4] = bflo(wv.z); wf[5] = bfhi(wv.z); wf[6] = bflo(wv.w); wf[7] = bfhi(wv.w);
            #pragma unroll
            for (int u = 0; u < 8; ++u) s += aS[k + u] * wf[u];
        }
        xp_s[(size_t)dirb * (40 * 16 * 768) + ((size_t)i2 * 16 + d) * 768 + oo] = f2h(s);
    }
}

// ---------------------------------------------------------------------------
// K6: cosine sims + 64->32 MLP + mask. grid = 512 ((b,m) pairs).
// ---------------------------------------------------------------------------
__global__ __launch_bounds__(256) void k_final(
    const int* __restrict__ men_sent_idx, const int* __restrict__ can_ent_idx,
    const void* __restrict__ cand_mask, const void* __restrict__ embed_ent,
    const float* __restrict__ each_sent, const float* __restrict__ doc_embs,
    const void* __restrict__ mlp_w, const void* __restrict__ mlp_b,
    void* __restrict__ out, const int* __restrict__ modep)
{
    const int bm = blockIdx.x;
    const int b = bm >> 5;
    __shared__ float sv[512], dv[512];
    __shared__ float red[256];
    __shared__ float ssA[32], dsA[32];
    __shared__ float norms[2];
    const int m = modep[0];
    const int tid = threadIdx.x;
    const int sidx = men_sent_idx[bm];
    const float* svp = each_sent + ((size_t)b * 40 + sidx) * 512;
    const float* dvp = doc_embs + (size_t)b * 512;
    float pa = 0.f, pd = 0.f;
    for (int j = tid; j < 512; j += 256) {
        float a = svp[j], d0 = dvp[j];
        sv[j] = a; dv[j] = d0; pa += a * a; pd += d0 * d0;
    }
    red[tid] = pa; __syncthreads();
    for (int s = 128; s > 0; s >>= 1) { if (tid < s) red[tid] += red[tid + s]; __syncthreads(); }
    if (tid == 0) norms[0] = sqrtf(red[0]);
    __syncthreads();
    red[tid] = pd; __syncthreads();
    for (int s = 128; s > 0; s >>= 1) { if (tid < s) red[tid] += red[tid + s]; __syncthreads(); }
    if (tid == 0) norms[1] = sqrtf(red[0]);
    __syncthreads();

    const int c = tid >> 3, jg = tid & 7;
    const int ei = can_ent_idx[(size_t)bm * 32 + c];
    float dsv = 0.f, ddv = 0.f, ne = 0.f;
    for (int k = 0; k < 64; k += 8) {
        float wf[8];
        ld8f(embed_ent, (size_t)ei * 512 + jg * 64 + k, m, wf);
        const int base = jg * 64 + k;
        #pragma unroll
        for (int u = 0; u < 8; ++u) {
            dsv += sv[base + u] * wf[u];
            ddv += dv[base + u] * wf[u];
            ne  += wf[u] * wf[u];
        }
    }
    #pragma unroll
    for (int d0 = 1; d0 < 8; d0 <<= 1) {
        dsv += __shfl_xor(dsv, d0);
        ddv += __shfl_xor(ddv, d0);
        ne  += __shfl_xor(ne, d0);
    }
    if (jg == 0) {
        const float nen = sqrtf(ne);
        const float cm = ldsc(cand_mask, (size_t)bm * 32 + c, m);
        ssA[c] = dsv / fmaxf(norms[0] * nen, 1e-8f) * cm;
        dsA[c] = ddv / fmaxf(norms[1] * nen, 1e-8f) * cm;
    }
    __syncthreads();
    if (tid < 32) {
        float o = ldsc(mlp_b, tid, m);
        for (int j2 = 0; j2 < 32; ++j2) {
            o += ssA[j2] * ldsc(mlp_w, tid * 64 + j2, m);
            o += dsA[j2] * ldsc(mlp_w, tid * 64 + 32 + j2, m);
        }
        const float maskv = (ssA[tid] != 0.f) ? 1.f : 0.f;
        const float v = fin(o * maskv);
        if (m) ((unsigned short*)out)[(size_t)bm * 32 + tid] = f2bfraw(v);
        else   ((float*)out)[(size_t)bm * 32 + tid] = v;
    }
}

// ---------------------------------------------------------------------------
extern "C" void kernel_launch(void* const* d_in, const int* in_sizes, int n_in,
                              void* d_out, int out_size, void* d_ws, size_t ws_size,
                              hipStream_t stream)
{
    (void)in_sizes; (void)n_in; (void)out_size;
    const int* batch_doc    = (const int*)d_in[0];
    const int* sent_order   = (const int*)d_in[1];
    const int* length_sent  = (const int*)d_in[2];
    const int* length_doc   = (const int*)d_in[3];
    const int* men_sent_idx = (const int*)d_in[4];
    const int* can_ent_idx  = (const int*)d_in[5];
    const void* cand_mask = d_in[6];
    const void* embed_doc = d_in[7];
    const void* embed_ent = d_in[8];
    const void* wWihF = d_in[9];
    const void* wWhhF = d_in[10];
    const void* wBihF = d_in[11];
    const void* wBhhF = d_in[12];
    const void* wWihB = d_in[13];
    const void* wWhhB = d_in[14];
    const void* wBihB = d_in[15];
    const void* wBhhB = d_in[16];
    const void* wLinW = d_in[17];
    const void* wLinB = d_in[18];
    const void* wAttw = d_in[19];
    const void* sWihF = d_in[20];
    const void* sWhhF = d_in[21];
    const void* sBihF = d_in[22];
    const void* sBhhF = d_in[23];
    const void* sWihB = d_in[24];
    const void* sWhhB = d_in[25];
    const void* sBihB = d_in[26];
    const void* sBhhB = d_in[27];
    const void* sLinW = d_in[28];
    const void* sLinB = d_in[29];
    const void* sAttw = d_in[30];
    const void* mlpW  = d_in[31];
    const void* mlpB  = d_in[32];

    const size_t N_EMB = (size_t)50000 * 512;
    // head = mode + 4 swz + wih_w + lin_h + swih + slin_h + sent_pad
    const size_t HEAD =
        256 + 4 * (size_t)196608 * 2 +
        (size_t)1536 * 512 * 2 + (size_t)512 * 512 * 2 +
        (size_t)1536 * 512 * 2 + (size_t)512 * 512 * 2 +
        (size_t)328192 * 4;
    // sentence-phase region (aliases word-phase region):
    //   each_sent 1,310,720 | xp_s 1,966,080 | enc_s 655,360 | att_s 2,816 | doc_embs 32,768
    const size_t SENT_REGION = 1310720 + 1966080 + 655360 + 2816 + 32768;
    auto need = [&](int nbq, int e) -> size_t {
        size_t word = (size_t)nbq * (196608 + 65536 + 256);  // xp_c + enc_c(fp16) + att_c
        size_t region = word > SENT_REGION ? word : SENT_REGION;
        return HEAD + region + (e ? N_EMB * 2 : 0) + (1u << 20);
    };
    // Prefer LARGER nb (fewer sequential GRU dispatches -> more CUs busy)
    // over embedding bf16 conversion.
    int emb_cvt = 1, nb = 320;
    {
        const int ladder[6] = {640, 320, 160, 80, 40, 16};
        bool found = false;
        for (int i = 0; i < 6 && !found; ++i)
            for (int e = 1; e >= 0 && !found; --e)
                if (need(ladder[i], e) <= ws_size) { emb_cvt = e; nb = ladder[i]; found = true; }
    }

    char* base = (char*)d_ws;
    size_t off = 0;
    auto take = [&](size_t bytes) -> void* {
        void* p = base + off; off += (bytes + 255) & ~(size_t)255; return p;
    };
    int* mode = (int*)take(256);
    unsigned short* swzWF = (unsigned short*)take((size_t)196608 * 2);
    unsigned short* swzWB = (unsigned short*)take((size_t)196608 * 2);
    unsigned short* swzSF = (unsigned short*)take((size_t)196608 * 2);
    unsigned short* swzSB = (unsigned short*)take((size_t)196608 * 2);
    unsigned short* wih_w = (unsigned short*)take((size_t)1536 * 512 * 2);
    unsigned short* lin_h = (unsigned short*)take((size_t)512 * 512 * 2);   // fp16
    unsigned short* swih  = (unsigned short*)take((size_t)1536 * 512 * 2);
    unsigned short* slin_h= (unsigned short*)take((size_t)512 * 512 * 2);   // fp16
    float* sent_pad  = (float*)take((size_t)328192 * 4);

    size_t word_bytes = (size_t)nb * (196608 + 65536 + 256);
    size_t region_bytes = word_bytes > SENT_REGION ? word_bytes : SENT_REGION;
    char* region = (char*)take(region_bytes);
    // word-phase layout
    unsigned short* xp_c  = (unsigned short*)region;
    unsigned short* enc_c = (unsigned short*)(region + (size_t)nb * 196608);
    float* att_c          = (float*)(region + (size_t)nb * 196608 + (size_t)nb * 65536);
    // sentence-phase layout (aliases the above; live only after word loop)
    float* each_sent      = (float*)region;
    unsigned short* xp_s  = (unsigned short*)(region + 1310720);
    unsigned short* enc_s = (unsigned short*)(region + 1310720 + 1966080);
    float* att_s          = (float*)(region + 1310720 + 1966080 + 655360);
    float* doc_embs       = (float*)(region + 1310720 + 1966080 + 655360 + 2816);

    unsigned short* emb_bf = emb_cvt ? (unsigned short*)take(N_EMB * 2) : nullptr;

    // ---- probe + prep ----
    k_probe<<<1, 64, 0, stream>>>((const unsigned short*)wWhhF, mode);
    p_whh_swz<<<96, 256, 0, stream>>>(wWhhF, swzWF, mode);
    p_whh_swz<<<96, 256, 0, stream>>>(wWhhB, swzWB, mode);
    p_whh_swz<<<96, 256, 0, stream>>>(sWhhF, swzSF, mode);
    p_whh_swz<<<96, 256, 0, stream>>>(sWhhB, swzSB, mode);
    p_cvt<<<256, 256, 0, stream>>>(wWihF, wih_w, 768 * 512, mode);
    p_cvt<<<256, 256, 0, stream>>>(wWihB, wih_w + (size_t)768 * 512, 768 * 512, mode);
    p_cvt_h<<<256, 256, 0, stream>>>(wLinW, lin_h, 512 * 512, mode);
    p_cvt<<<256, 256, 0, stream>>>(sWihF, swih, 768 * 512, mode);
    p_cvt<<<256, 256, 0, stream>>>(sWihB, swih + (size_t)768 * 512, 768 * 512, mode);
    p_cvt_h<<<256, 256, 0, stream>>>(sLinW, slin_h, 512 * 512, mode);
    if (emb_cvt) p_cvt<<<2048, 256, 0, stream>>>(embed_doc, emb_bf, (int)N_EMB, mode);

    const void* embA = emb_cvt ? (const void*)emb_bf : embed_doc;
    const int* amode = emb_cvt ? (mode + 1) : mode;

    // ---- word level, phased over sentence chunks ----
    for (int b0 = 0; b0 < 640; b0 += nb) {
        k_xp_word<<<dim3(nb, 6), 256, 0, stream>>>(embA, batch_doc, wih_w,
                                                   wBihF, wBihB, xp_c, b0, nb, amode, mode);
        k_gru<<<2 * (nb / 16), 512, 0, stream>>>(xp_c, swzWF, swzWB, wBhhF, wBhhB,
                                                 length_sent + b0, enc_c, 64, nb, mode);
        k_att<<<nb, 256, 0, stream>>>(enc_c, lin_h, wLinB, wAttw, att_c, mode);
        k_softsum<<<nb, 256, 0, stream>>>(att_c, enc_c, length_sent + b0,
                                          sent_pad + (size_t)(1 + b0) * 512,
                                          (b0 == 0) ? sent_pad : nullptr, 64, nb);
    }
    // ---- sentence level ----
    k_sent_xp<<<640, 256, 0, stream>>>(sent_order, sent_pad, swih, sBihF, sBihB,
                                       each_sent, xp_s, mode);
    k_gru<<<2, 512, 0, stream>>>(xp_s, swzSF, swzSB, sBhhF, sBhhB,
                                 length_doc, enc_s, 40, 16, mode);
    k_att<<<10, 256, 0, stream>>>(enc_s, slin_h, sLinB, sAttw, att_s, mode);
    k_softsum<<<16, 256, 0, stream>>>(att_s, enc_s, length_doc, doc_embs, nullptr, 40, 16);
    // ---- scoring ----
    k_final<<<512, 256, 0, stream>>>(men_sent_idx, can_ent_idx, cand_mask, embed_ent,
                                     each_sent, doc_embs, mlpW, mlpB, d_out, mode);
}

// Round 3
// 1359.273 us; speedup vs baseline: 1.0193x; 1.0193x over previous
//
#include <hip/hip_runtime.h>
#include <cstdint>
#include <cstddef>

// ---------------------------------------------------------------------------
// HAN forward on gfx950. Float input dtype (fp32 vs bf16) unknown at build
// time -> probe kernel writes mode flag; prep kernels convert all hot-path
// operands to bf16/fp16 once (Whh swizzled into MFMA-fragment order for the
// 8-wave GRU). GRU: 512-thread blocks, h fp32 in registers + hi/lo bf16 LDS
// mirrors (double-buffered, 1 barrier/step), B half-persisted in registers
// (groups 0..2) + half streamed from L2 (groups 3..5), K split in 2 phases.
// SINGLE-PASS word level (nb=640, one 80-block GRU dispatch) made to fit the
// workspace by liveness-overlaying: wih_w lives in the enc region (dead after
// xp_word), lin + all sentence-phase buffers live in the xp region (dead
// after gru). Chunked fallback keeps the round-2 layout.
// ---------------------------------------------------------------------------

typedef __attribute__((ext_vector_type(8))) short bf16x8;   // 8 bf16 = 4 VGPR
typedef __attribute__((ext_vector_type(8))) _Float16 f16x8; // 8 fp16 = 4 VGPR
typedef __attribute__((ext_vector_type(4))) float f32x4;

__device__ __forceinline__ float bfraw2f(unsigned int u16) {
    unsigned int x = u16 << 16; float f; __builtin_memcpy(&f, &x, 4); return f;
}
__device__ __forceinline__ unsigned short f2bfraw(float f) {  // RNE
    unsigned int u; __builtin_memcpy(&u, &f, 4);
    unsigned int r = u + 0x7fffu + ((u >> 16) & 1u);
    return (unsigned short)(r >> 16);
}
__device__ __forceinline__ unsigned short f2h(float f) {
    _Float16 h = (_Float16)f; unsigned short u; __builtin_memcpy(&u, &h, 2); return u;
}
__device__ __forceinline__ float h2f(unsigned short u) {
    _Float16 h; __builtin_memcpy(&h, &u, 2); return (float)h;
}
__device__ __forceinline__ float bflo(unsigned int p) {
    unsigned int x = p << 16; float f; __builtin_memcpy(&f, &x, 4); return f;
}
__device__ __forceinline__ float bfhi(unsigned int p) {
    unsigned int x = p & 0xffff0000u; float f; __builtin_memcpy(&f, &x, 4); return f;
}
__device__ __forceinline__ float fast_sigmoid(float x) { return 1.f / (1.f + __expf(-x)); }
__device__ __forceinline__ float fast_tanh(float x) {
    x = fminf(fmaxf(x, -30.f), 30.f);
    float e = __expf(2.f * x);
    return (e - 1.f) / (e + 1.f);
}
__device__ __forceinline__ float fin(float x) {
    return (x == x && fabsf(x) < 1e30f) ? x : 0.f;
}

// ---- dual-mode input adapters (m=1: bf16 u16 buffer, m=0: fp32 buffer) ----
__device__ __forceinline__ float ldsc(const void* p, size_t i, int m) {
    return m ? bfraw2f(((const unsigned short*)p)[i]) : ((const float*)p)[i];
}
__device__ __forceinline__ bf16x8 ld8bf(const void* p, size_t ei, int m) {
    if (m) return *(const bf16x8*)((const unsigned short*)p + ei);
    const float* f = (const float*)p + ei;
    f32x4 a = *(const f32x4*)f, b = *(const f32x4*)(f + 4);
    bf16x8 r;
    r[0] = (short)f2bfraw(a[0]); r[1] = (short)f2bfraw(a[1]);
    r[2] = (short)f2bfraw(a[2]); r[3] = (short)f2bfraw(a[3]);
    r[4] = (short)f2bfraw(b[0]); r[5] = (short)f2bfraw(b[1]);
    r[6] = (short)f2bfraw(b[2]); r[7] = (short)f2bfraw(b[3]);
    return r;
}
__device__ __forceinline__ void ld8f(const void* p, size_t ei, int m, float* o) {
    if (m) {
        uint4 wv = *(const uint4*)((const unsigned short*)p + ei);
        o[0] = bflo(wv.x); o[1] = bfhi(wv.x); o[2] = bflo(wv.y); o[3] = bfhi(wv.y);
        o[4] = bflo(wv.z); o[5] = bfhi(wv.z); o[6] = bflo(wv.w); o[7] = bfhi(wv.w);
    } else {
        const float* f = (const float*)p + ei;
        #pragma unroll
        for (int i = 0; i < 8; ++i) o[i] = f[i];
    }
}

// ---------------------------------------------------------------------------
// K0: dtype probe. flag[0] = mode (1=bf16, 0=fp32); flag[1] = 1 always.
// ---------------------------------------------------------------------------
__global__ void k_probe(const unsigned short* __restrict__ w, int* __restrict__ flag) {
    if (threadIdx.x == 0) {
        int bad = 0;
        for (int i = 0; i < 512; ++i) {
            float v = bfraw2f(w[i]);
            if (!(fabsf(v) <= 1.0f)) bad++;
        }
        flag[0] = (bad == 0) ? 1 : 0;
        flag[1] = 1;
    }
}

// ---------------------------------------------------------------------------
// P1a: generic dual-mode -> bf16 convert.  P1b: -> fp16 convert.
// ---------------------------------------------------------------------------
__global__ void p_cvt(const void* __restrict__ src, unsigned short* __restrict__ dst,
                      int n, const int* __restrict__ modep) {
    const int m = modep[0];
    for (int i = blockIdx.x * 256 + threadIdx.x; i < n; i += gridDim.x * 256)
        dst[i] = f2bfraw(ldsc(src, i, m));
}
__global__ void p_cvt_h(const void* __restrict__ src, unsigned short* __restrict__ dst,
                        int n, const int* __restrict__ modep) {
    const int m = modep[0];
    for (int i = blockIdx.x * 256 + threadIdx.x; i < n; i += gridDim.x * 256)
        dst[i] = f2h(ldsc(src, i, m));
}

// ---------------------------------------------------------------------------
// P2: Whh (768x256) -> bf16 MFMA-fragment order for the 8-wave GRU.
// ---------------------------------------------------------------------------
__global__ void p_whh_swz(const void* __restrict__ whh, unsigned short* __restrict__ dst,
                          const int* __restrict__ modep) {
    const int m = modep[0];
    const int idx = blockIdx.x * 256 + threadIdx.x;    // 24576 = 8*6*8*64
    if (idx >= 24576) return;
    const int lane = idx & 63, ks = (idx >> 6) & 7;
    const int g = (idx >> 9) % 6, w = idx / 3072;
    const int lm = lane & 15, q = lane >> 4;
    const int reg = g >> 1, nt = g & 1;
    const int row = reg * 256 + w * 32 + nt * 16 + lm;
    const size_t src = (size_t)row * 256 + ks * 32 + q * 8;
    const size_t d = (size_t)idx * 8;
    #pragma unroll
    for (int e = 0; e < 8; ++e) dst[d + e] = f2bfraw(ldsc(whh, src + e, m));
}

// ---------------------------------------------------------------------------
// K1: gathered word projection. xp[dir][t*nb+bl][768] fp16. grid (nb, 6).
// ---------------------------------------------------------------------------
__global__ __launch_bounds__(256, 2) void k_xp_word(
    const void* __restrict__ embA, const int* __restrict__ batch_doc,
    const unsigned short* __restrict__ wih,       // bf16 [1536][512]
    const void* __restrict__ bih_f, const void* __restrict__ bih_b,
    unsigned short* __restrict__ xp, int b0, int nb,
    const int* __restrict__ amode, const int* __restrict__ modep)
{
    __shared__ unsigned short As[64][40];
    __shared__ unsigned short Bs[256][40];
    const int am = amode[0], m = modep[0];
    const int bm = blockIdx.x, bc = blockIdx.y;
    const int tid = threadIdx.x;
    const int wave = tid >> 6, lane = tid & 63, lm = lane & 15, q = lane >> 4;
    const int arow = tid >> 2, akoff = (tid & 3) * 8;
    const int r = bm * 64 + arow;
    const int tt = r / nb, bl = r - tt * nb;
    const size_t aei = (size_t)batch_doc[(b0 + bl) * 64 + tt] * 512 + akoff;

    const f32x4 fzero = {0.f, 0.f, 0.f, 0.f};
    f32x4 acc[4][4];
    #pragma unroll
    for (int i = 0; i < 4; ++i)
        #pragma unroll
        for (int j = 0; j < 4; ++j) acc[i][j] = fzero;

    for (int kt = 0; kt < 16; ++kt) {
        *(bf16x8*)&As[arow][akoff] = ld8bf(embA, aei + kt * 32, am);
        #pragma unroll
        for (int ld = 0; ld < 4; ++ld) {
            int e = ld * 256 + tid;
            int n = e >> 2, koff = (e & 3) * 8;
            int gn = bc * 256 + n;
            *(uint4*)&Bs[n][koff] = *(const uint4*)(wih + (size_t)gn * 512 + kt * 32 + koff);
        }
        __syncthreads();
        bf16x8 af[4], bv[4];
        #pragma unroll
        for (int mt = 0; mt < 4; ++mt) af[mt] = *(const bf16x8*)&As[mt * 16 + lm][q * 8];
        #pragma unroll
        for (int nt = 0; nt < 4; ++nt) bv[nt] = *(const bf16x8*)&Bs[wave * 64 + nt * 16 + lm][q * 8];
        #pragma unroll
        for (int mt = 0; mt < 4; ++mt)
            #pragma unroll
            for (int nt = 0; nt < 4; ++nt)
                acc[mt][nt] = __builtin_amdgcn_mfma_f32_16x16x32_bf16(af[mt], bv[nt], acc[mt][nt], 0, 0, 0);
        __syncthreads();
    }

    const size_t XPT = (size_t)64 * nb * 768;
    #pragma unroll
    for (int nt = 0; nt < 4; ++nt) {
        const int cn = bc * 256 + wave * 64 + nt * 16 + lm;
        const int dirb = (cn >= 768);
        const int o = cn - dirb * 768;
        const float bias = ldsc(dirb ? bih_b : bih_f, o, m);
        #pragma unroll
        for (int mt = 0; mt < 4; ++mt)
            #pragma unroll
            for (int j = 0; j < 4; ++j) {
                const int rr = bm * 64 + mt * 16 + q * 4 + j;
                xp[(dirb ? XPT : 0) + (size_t)rr * 768 + o] = f2h(acc[mt][nt][j] + bias);
            }
    }
}

// ---------------------------------------------------------------------------
// K2: pipelined GRU. 512 threads (8 waves, 2/SIMD). Wave w owns hidden cols
// [w*32, w*32+32). h fp32 in REGISTERS; hi/lo bf16 mirrors + xp tile in
// double-buffered LDS -> 1 barrier/step. B groups 0..2 persisted in regs,
// 3..5 streamed from L2; K split in 2 phases. enc written fp16 (|h|<=1).
// grid = 2*(NB/16), dir = blockIdx&1.
// ---------------------------------------------------------------------------
__global__ __launch_bounds__(512, 2) void k_gru(
    const unsigned short* __restrict__ xp,
    const unsigned short* __restrict__ wswz_f,      // bf16 swizzled 196608
    const unsigned short* __restrict__ wswz_b,
    const void* __restrict__ bhh_f, const void* __restrict__ bhh_b,
    const int* __restrict__ lens, unsigned short* __restrict__ enc, int T, int NB,
    const int* __restrict__ modep)
{
    __shared__ unsigned short hHi[2][16][264];   // pitch 528B
    __shared__ unsigned short hLo[2][16][264];
    __shared__ unsigned short xpS[2][16][776];   // fp16, pitch 1552B
    __shared__ float bhhS[768];
    __shared__ int lensS[16];
    const int m = modep[0];
    const int tid = threadIdx.x;
    const int w = tid >> 6, lane = tid & 63, lm = lane & 15, q = lane >> 4;
    const int dir = blockIdx.x & 1, sg = blockIdx.x >> 1;
    const int s0 = sg << 4;
    const unsigned short* wsw =
        (dir ? wswz_b : wswz_f) + (size_t)w * 24576 + (size_t)lane * 8;
    const void* bhh = dir ? bhh_b : bhh_f;
    const unsigned short* xpd = xp + (dir ? (size_t)T * NB * 768 : 0);

    for (int e = tid; e < 16 * 264; e += 512) {
        (&hHi[0][0][0])[e] = 0; (&hLo[0][0][0])[e] = 0;
    }
    for (int j = tid; j < 768; j += 512) bhhS[j] = ldsc(bhh, j, m);
    if (tid < 16) lensS[tid] = lens[s0 + tid];

    // persistent B: groups 0..2 (24 fragments = 96 regs), loaded once.
    bf16x8 bper[3][8];
    #pragma unroll
    for (int g = 0; g < 3; ++g)
        #pragma unroll
        for (int ks = 0; ks < 8; ++ks)
            bper[g][ks] = *(const bf16x8*)(wsw + (size_t)(g * 8 + ks) * 512);

    // prologue: stage xp(t0) into xpS[0]
    {
        const int t0 = dir ? (T - 1) : 0;
        const unsigned short* xrow = xpd + ((size_t)t0 * NB + s0) * 768;
        #pragma unroll
        for (int i = 0; i < 3; ++i) {
            int e = tid + i * 512;                 // [0,1536) dwordx4 slots
            uint4 v = *(const uint4*)(xrow + e * 8);
            *(uint4*)&xpS[0][e / 96][(e % 96) * 8] = v;
        }
    }
    __syncthreads();

    const f32x4 fzero = {0.f, 0.f, 0.f, 0.f};
    float hreg[2][4] = {};                         // h fp32, lane-owned
    uint4 stg[3];
    for (int step = 0; step < T; ++step) {
        const int t = dir ? (T - 1 - step) : step;
        const int cur = step & 1, nxt = cur ^ 1;

        // prefetch next step's xp tile into registers (overlaps everything)
        const bool havenext = (step + 1 < T);
        if (havenext) {
            const int tn = dir ? (T - 2 - step) : (step + 1);
            const unsigned short* xrow = xpd + ((size_t)tn * NB + s0) * 768;
            #pragma unroll
            for (int i = 0; i < 3; ++i)
                stg[i] = *(const uint4*)(xrow + (tid + i * 512) * 8);
        }

        f32x4 acc[6];
        #pragma unroll
        for (int i = 0; i < 6; ++i) acc[i] = fzero;

        // two K-phases: ks 0-3 then 4-7.
        #pragma unroll
        for (int ph = 0; ph < 2; ++ph) {
            const int kb = ph * 4;
            bf16x8 ahi[4], alo[4];
            #pragma unroll
            for (int k = 0; k < 4; ++k) {
                ahi[k] = *(const bf16x8*)&hHi[cur][lm][(kb + k) * 32 + q * 8];
                alo[k] = *(const bf16x8*)&hLo[cur][lm][(kb + k) * 32 + q * 8];
            }
            bf16x8 bs3[4], bs4[4], bs5[4];
            #pragma unroll
            for (int k = 0; k < 4; ++k) {
                bs3[k] = *(const bf16x8*)(wsw + (size_t)(24 + kb + k) * 512);
                bs4[k] = *(const bf16x8*)(wsw + (size_t)(32 + kb + k) * 512);
                bs5[k] = *(const bf16x8*)(wsw + (size_t)(40 + kb + k) * 512);
            }
            #pragma unroll
            for (int g = 0; g < 3; ++g)
                #pragma unroll
                for (int k = 0; k < 4; ++k) {
                    acc[g] = __builtin_amdgcn_mfma_f32_16x16x32_bf16(ahi[k], bper[g][kb + k], acc[g], 0, 0, 0);
                    acc[g] = __builtin_amdgcn_mfma_f32_16x16x32_bf16(alo[k], bper[g][kb + k], acc[g], 0, 0, 0);
                }
            #pragma unroll
            for (int k = 0; k < 4; ++k) {
                acc[3] = __builtin_amdgcn_mfma_f32_16x16x32_bf16(ahi[k], bs3[k], acc[3], 0, 0, 0);
                acc[3] = __builtin_amdgcn_mfma_f32_16x16x32_bf16(alo[k], bs3[k], acc[3], 0, 0, 0);
                acc[4] = __builtin_amdgcn_mfma_f32_16x16x32_bf16(ahi[k], bs4[k], acc[4], 0, 0, 0);
                acc[4] = __builtin_amdgcn_mfma_f32_16x16x32_bf16(alo[k], bs4[k], acc[4], 0, 0, 0);
                acc[5] = __builtin_amdgcn_mfma_f32_16x16x32_bf16(ahi[k], bs5[k], acc[5], 0, 0, 0);
                acc[5] = __builtin_amdgcn_mfma_f32_16x16x32_bf16(alo[k], bs5[k], acc[5], 0, 0, 0);
            }
        }

        // gates: lane element (s=q*4+j, col=w*32+nt*16+lm), nt in {0,1}
        #pragma unroll
        for (int nt = 0; nt < 2; ++nt) {
            const int col = w * 32 + nt * 16 + lm;
            const float br = bhhS[col], bz = bhhS[256 + col], bn = bhhS[512 + col];
            #pragma unroll
            for (int j = 0; j < 4; ++j) {
                const int s = q * 4 + j;
                const float xr = h2f(xpS[cur][s][col]);
                const float xz = h2f(xpS[cur][s][256 + col]);
                const float xn = h2f(xpS[cur][s][512 + col]);
                const float rr = fast_sigmoid(xr + acc[nt][j] + br);
                const float zz = fast_sigmoid(xz + acc[2 + nt][j] + bz);
                const float nn = fast_tanh(xn + rr * (acc[4 + nt][j] + bn));
                const float hold = hreg[nt][j];
                float hnew = (1.f - zz) * nn + zz * hold;
                const bool v = (t < lensS[s]);
                hnew = v ? hnew : hold;
                hreg[nt][j] = hnew;
                const unsigned short uh = f2bfraw(hnew);
                hHi[nxt][s][col] = uh;
                hLo[nxt][s][col] = f2bfraw(hnew - bfraw2f(uh));
                enc[((size_t)t * NB + s0 + s) * 512 + (size_t)dir * 256 + col] = f2h(v ? hnew : 0.f);
            }
        }

        if (havenext) {    // write prefetched xp tile into the other buffer
            #pragma unroll
            for (int i = 0; i < 3; ++i) {
                int e = tid + i * 512;
                *(uint4*)&xpS[nxt][e / 96][(e % 96) * 8] = stg[i];
            }
        }
        __syncthreads();   // h[nxt] + xpS[nxt] visible for next step
    }
}

// ---------------------------------------------------------------------------
// K3: attention scores, GEMM (M x 512)@(512x512) + fused tanh*attw reduce.
// enc and lin are fp16 -> f16 MFMA.
// ---------------------------------------------------------------------------
__global__ __launch_bounds__(256, 1) void k_att(
    const unsigned short* __restrict__ enc,       // fp16 [M][512]
    const unsigned short* __restrict__ lin_w,     // fp16 [512][512]
    const void* __restrict__ lin_b, const void* __restrict__ attw,
    float* __restrict__ att_out, const int* __restrict__ modep)
{
    __shared__ unsigned short As[64][40];
    __shared__ unsigned short Bs[512][40];
    __shared__ float att_part[4][64];
    const int m = modep[0];
    const int bm = blockIdx.x;
    const int tid = threadIdx.x;
    const int wave = tid >> 6, lane = tid & 63, lm = lane & 15, q = lane >> 4;
    const int arow = tid >> 2, akoff = (tid & 3) * 8;
    const unsigned short* aptr = enc + (size_t)(bm * 64 + arow) * 512 + akoff;

    const f32x4 fzero = {0.f, 0.f, 0.f, 0.f};
    f32x4 acc[4][8];
    #pragma unroll
    for (int i = 0; i < 4; ++i)
        #pragma unroll
        for (int j = 0; j < 8; ++j) acc[i][j] = fzero;

    for (int kt = 0; kt < 16; ++kt) {
        *(uint4*)&As[arow][akoff] = *(const uint4*)(aptr + kt * 32);
        #pragma unroll
        for (int ld = 0; ld < 8; ++ld) {
            int e = ld * 256 + tid;
            int n = e >> 2, koff = (e & 3) * 8;
            *(uint4*)&Bs[n][koff] = *(const uint4*)(lin_w + (size_t)n * 512 + kt * 32 + koff);
        }
        __syncthreads();
        f16x8 af[4];
        #pragma unroll
        for (int mt = 0; mt < 4; ++mt) af[mt] = *(const f16x8*)&As[mt * 16 + lm][q * 8];
        #pragma unroll
        for (int nt = 0; nt < 8; ++nt) {
            f16x8 bv = *(const f16x8*)&Bs[wave * 128 + nt * 16 + lm][q * 8];
            #pragma unroll
            for (int mt = 0; mt < 4; ++mt)
                acc[mt][nt] = __builtin_amdgcn_mfma_f32_16x16x32_f16(af[mt], bv, acc[mt][nt], 0, 0, 0);
        }
        __syncthreads();
    }

    float part[4][4] = {};
    #pragma unroll
    for (int nt = 0; nt < 8; ++nt) {
        const int col = wave * 128 + nt * 16 + lm;
        const float lb = ldsc(lin_b, col, m);
        const float aw = ldsc(attw, col, m);
        #pragma unroll
        for (int mt = 0; mt < 4; ++mt)
            #pragma unroll
            for (int j = 0; j < 4; ++j)
                part[mt][j] += fast_tanh(acc[mt][nt][j] + lb) * aw;
    }
    #pragma unroll
    for (int mt = 0; mt < 4; ++mt)
        #pragma unroll
        for (int j = 0; j < 4; ++j) {
            float v = part[mt][j];
            #pragma unroll
            for (int d0 = 1; d0 < 16; d0 <<= 1) v += __shfl_xor(v, d0);
            part[mt][j] = v;
        }
    if (lm == 0) {
        #pragma unroll
        for (int mt = 0; mt < 4; ++mt)
            #pragma unroll
            for (int j = 0; j < 4; ++j)
                att_part[wave][mt * 16 + q * 4 + j] = part[mt][j];
    }
    __syncthreads();
    if (tid < 64)
        att_out[(size_t)bm * 64 + tid] =
            att_part[0][tid] + att_part[1][tid] + att_part[2][tid] + att_part[3][tid];
}

// ---------------------------------------------------------------------------
// K4: masked softmax over t + weighted sum of enc (fp16) rows. grid = NB.
// ---------------------------------------------------------------------------
__global__ __launch_bounds__(256) void k_softsum(
    const float* __restrict__ att, const unsigned short* __restrict__ enc,
    const int* __restrict__ lens, float* __restrict__ out,
    float* __restrict__ zero_row, int T, int NB)
{
    __shared__ float eS[64];
    __shared__ float dS;
    const int bb = blockIdx.x, tid = threadIdx.x;
    if (zero_row && bb == 0) { for (int j = tid; j < 512; j += 256) zero_row[j] = 0.f; }
    const int len = lens[bb];
    if (tid < T) {
        float a = fminf(att[(size_t)tid * NB + bb], 50.f);
        eS[tid] = (tid < len) ? __expf(a) : 0.f;
    }
    __syncthreads();
    if (tid == 0) { float s = 0.f; for (int t2 = 0; t2 < T; ++t2) s += eS[t2]; dS = s + 1e-4f; }
    __syncthreads();
    const float inv = 1.f / dS;
    for (int j = tid; j < 512; j += 256) {
        float a0 = 0.f;
        for (int t2 = 0; t2 < T; ++t2) a0 += eS[t2] * h2f(enc[((size_t)t2 * NB + bb) * 512 + j]);
        out[(size_t)bb * 512 + j] = fin(a0 * inv);
    }
}

// ---------------------------------------------------------------------------
// K5: sentence gather + sentence input projection; writes xp_s fp16.
// ---------------------------------------------------------------------------
__global__ __launch_bounds__(256) void k_sent_xp(
    const int* __restrict__ sent_order, const float* __restrict__ sent_pad,
    const unsigned short* __restrict__ swih,      // bf16 [1536][512]
    const void* __restrict__ bih_f, const void* __restrict__ bih_b,
    float* __restrict__ each_sent, unsigned short* __restrict__ xp_s,
    const int* __restrict__ modep)
{
    __shared__ float aS[512];
    const int m = modep[0];
    const int r = blockIdx.x, tid = threadIdx.x;
    const int idx = sent_order[r];
    const float* src = sent_pad + (size_t)idx * 512;
    for (int j = tid; j < 512; j += 256) { float v = src[j]; aS[j] = v; each_sent[(size_t)r * 512 + j] = v; }
    __syncthreads();
    const int d = r / 40, i2 = r % 40;
    #pragma unroll
    for (int p = 0; p < 6; ++p) {
        const int o = p * 256 + tid;
        const int dirb = (o >= 768);
        const int oo = o - dirb * 768;
        float s = ldsc(dirb ? bih_b : bih_f, oo, m);
        const unsigned short* wrow = swih + (size_t)o * 512;
        for (int k = 0; k < 512; k += 8) {
            const uint4 wv = *(const uint4*)(wrow + k);
            float wf[8];
            wf[0] = bflo(wv.x); wf[1] = bfhi(wv.x); wf[2] = bflo(wv.y); wf[3] = bfhi(wv.y);
            wf[4] = bflo(wv.z); wf[5] = bfhi(wv.z); wf[6] = bflo(wv.w); wf[7] = bfhi(wv.w);
            #pragma unroll
            for (int u = 0; u < 8; ++u) s += aS[k + u] * wf[u];
        }
        xp_s[(size_t)dirb * (40 * 16 * 768) + ((size_t)i2 * 16 + d) * 768 + oo] = f2h(s);
    }
}

// ---------------------------------------------------------------------------
// K6: cosine sims + 64->32 MLP + mask. grid = 512 ((b,m) pairs).
// ---------------------------------------------------------------------------
__global__ __launch_bounds__(256) void k_final(
    const int* __restrict__ men_sent_idx, const int* __restrict__ can_ent_idx,
    const void* __restrict__ cand_mask, const void* __restrict__ embed_ent,
    const float* __restrict__ each_sent, const float* __restrict__ doc_embs,
    const void* __restrict__ mlp_w, const void* __restrict__ mlp_b,
    void* __restrict__ out, const int* __restrict__ modep)
{
    const int bm = blockIdx.x;
    const int b = bm >> 5;
    __shared__ float sv[512], dv[512];
    __shared__ float red[256];
    __shared__ float ssA[32], dsA[32];
    __shared__ float norms[2];
    const int m = modep[0];
    const int tid = threadIdx.x;
    const int sidx = men_sent_idx[bm];
    const float* svp = each_sent + ((size_t)b * 40 + sidx) * 512;
    const float* dvp = doc_embs + (size_t)b * 512;
    float pa = 0.f, pd = 0.f;
    for (int j = tid; j < 512; j += 256) {
        float a = svp[j], d0 = dvp[j];
        sv[j] = a; dv[j] = d0; pa += a * a; pd += d0 * d0;
    }
    red[tid] = pa; __syncthreads();
    for (int s = 128; s > 0; s >>= 1) { if (tid < s) red[tid] += red[tid + s]; __syncthreads(); }
    if (tid == 0) norms[0] = sqrtf(red[0]);
    __syncthreads();
    red[tid] = pd; __syncthreads();
    for (int s = 128; s > 0; s >>= 1) { if (tid < s) red[tid] += red[tid + s]; __syncthreads(); }
    if (tid == 0) norms[1] = sqrtf(red[0]);
    __syncthreads();

    const int c = tid >> 3, jg = tid & 7;
    const int ei = can_ent_idx[(size_t)bm * 32 + c];
    float dsv = 0.f, ddv = 0.f, ne = 0.f;
    for (int k = 0; k < 64; k += 8) {
        float wf[8];
        ld8f(embed_ent, (size_t)ei * 512 + jg * 64 + k, m, wf);
        const int base = jg * 64 + k;
        #pragma unroll
        for (int u = 0; u < 8; ++u) {
            dsv += sv[base + u] * wf[u];
            ddv += dv[base + u] * wf[u];
            ne  += wf[u] * wf[u];
        }
    }
    #pragma unroll
    for (int d0 = 1; d0 < 8; d0 <<= 1) {
        dsv += __shfl_xor(dsv, d0);
        ddv += __shfl_xor(ddv, d0);
        ne  += __shfl_xor(ne, d0);
    }
    if (jg == 0) {
        const float nen = sqrtf(ne);
        const float cm = ldsc(cand_mask, (size_t)bm * 32 + c, m);
        ssA[c] = dsv / fmaxf(norms[0] * nen, 1e-8f) * cm;
        dsA[c] = ddv / fmaxf(norms[1] * nen, 1e-8f) * cm;
    }
    __syncthreads();
    if (tid < 32) {
        float o = ldsc(mlp_b, tid, m);
        for (int j2 = 0; j2 < 32; ++j2) {
            o += ssA[j2] * ldsc(mlp_w, tid * 64 + j2, m);
            o += dsA[j2] * ldsc(mlp_w, tid * 64 + 32 + j2, m);
        }
        const float maskv = (ssA[tid] != 0.f) ? 1.f : 0.f;
        const float v = fin(o * maskv);
        if (m) ((unsigned short*)out)[(size_t)bm * 32 + tid] = f2bfraw(v);
        else   ((float*)out)[(size_t)bm * 32 + tid] = v;
    }
}

// ---------------------------------------------------------------------------
extern "C" void kernel_launch(void* const* d_in, const int* in_sizes, int n_in,
                              void* d_out, int out_size, void* d_ws, size_t ws_size,
                              hipStream_t stream)
{
    (void)in_sizes; (void)n_in; (void)out_size;
    const int* batch_doc    = (const int*)d_in[0];
    const int* sent_order   = (const int*)d_in[1];
    const int* length_sent  = (const int*)d_in[2];
    const int* length_doc   = (const int*)d_in[3];
    const int* men_sent_idx = (const int*)d_in[4];
    const int* can_ent_idx  = (const int*)d_in[5];
    const void* cand_mask = d_in[6];
    const void* embed_doc = d_in[7];
    const void* embed_ent = d_in[8];
    const void* wWihF = d_in[9];
    const void* wWhhF = d_in[10];
    const void* wBihF = d_in[11];
    const void* wBhhF = d_in[12];
    const void* wWihB = d_in[13];
    const void* wWhhB = d_in[14];
    const void* wBihB = d_in[15];
    const void* wBhhB = d_in[16];
    const void* wLinW = d_in[17];
    const void* wLinB = d_in[18];
    const void* wAttw = d_in[19];
    const void* sWihF = d_in[20];
    const void* sWhhF = d_in[21];
    const void* sBihF = d_in[22];
    const void* sBhhF = d_in[23];
    const void* sWihB = d_in[24];
    const void* sWhhB = d_in[25];
    const void* sBihB = d_in[26];
    const void* sBhhB = d_in[27];
    const void* sLinW = d_in[28];
    const void* sLinB = d_in[29];
    const void* sAttw = d_in[30];
    const void* mlpW  = d_in[31];
    const void* mlpB  = d_in[32];

    const size_t N_EMB = (size_t)50000 * 512;
    char* base = (char*)d_ws;

    // ======== single-pass layout (nb=640, liveness-overlaid) ========
    // word-phase live set: mode | swzWF | swzWB | att_c | xp_c | enc_c
    //   = 256 + 2*393,216 + 163,840 + 125,829,120 + 41,943,040 = 168,722,688 B
    const size_t SP_MODE  = 0;
    const size_t SP_SWZWF = 256;
    const size_t SP_SWZWB = SP_SWZWF + 393216;
    const size_t SP_ATTC  = SP_SWZWB + 393216;
    const size_t SP_XPC   = SP_ATTC + 163840;
    const size_t SP_ENCC  = SP_XPC + (size_t)125829120;
    const size_t SP_END   = SP_ENCC + (size_t)41943040;
    const bool single = (SP_END + 65536) <= ws_size;

    if (single) {
        int* mode             = (int*)(base + SP_MODE);
        unsigned short* swzWF = (unsigned short*)(base + SP_SWZWF);
        unsigned short* swzWB = (unsigned short*)(base + SP_SWZWB);
        float* att_c          = (float*)(base + SP_ATTC);
        unsigned short* xp_c  = (unsigned short*)(base + SP_XPC);
        unsigned short* enc_c = (unsigned short*)(base + SP_ENCC);
        // overlays: wih_w in enc region (dead after k_xp_word reads it).
        unsigned short* wih_w = enc_c;
        // overlays in xp region (written only AFTER word-level k_gru):
        char* xr = (char*)xp_c;
        unsigned short* lin_h  = (unsigned short*)(xr);                 //   524,288
        float* sent_pad        = (float*)(xr + 524288);                 // 1,312,768
        unsigned short* swzSF  = (unsigned short*)(xr + 1837056);       //   393,216
        unsigned short* swzSB  = (unsigned short*)(xr + 2230272);       //   393,216
        unsigned short* swih   = (unsigned short*)(xr + 2623488);       // 1,572,864
        unsigned short* slin_h = (unsigned short*)(xr + 4196352);       //   524,288
        float* each_sent       = (float*)(xr + 4720640);                // 1,310,720
        unsigned short* xp_s   = (unsigned short*)(xr + 6031360);       // 1,966,080
        unsigned short* enc_s  = (unsigned short*)(xr + 7997440);       //   655,360
        float* att_s           = (float*)(xr + 8652800);                //     2,560
        float* doc_embs        = (float*)(xr + 8655616);                //    32,768

        // ---- probe + word-phase prep ----
        k_probe<<<1, 64, 0, stream>>>((const unsigned short*)wWhhF, mode);
        p_whh_swz<<<96, 256, 0, stream>>>(wWhhF, swzWF, mode);
        p_whh_swz<<<96, 256, 0, stream>>>(wWhhB, swzWB, mode);
        p_cvt<<<256, 256, 0, stream>>>(wWihF, wih_w, 768 * 512, mode);
        p_cvt<<<256, 256, 0, stream>>>(wWihB, wih_w + (size_t)768 * 512, 768 * 512, mode);

        // ---- word level, single pass over all 640 sentences ----
        k_xp_word<<<dim3(640, 6), 256, 0, stream>>>(embed_doc, batch_doc, wih_w,
                                                    wBihF, wBihB, xp_c, 0, 640, mode, mode);
        k_gru<<<80, 512, 0, stream>>>(xp_c, swzWF, swzWB, wBhhF, wBhhB,
                                      length_sent, enc_c, 64, 640, mode);
        p_cvt_h<<<128, 256, 0, stream>>>(wLinW, lin_h, 512 * 512, mode);  // xp now dead
        k_att<<<640, 256, 0, stream>>>(enc_c, lin_h, wLinB, wAttw, att_c, mode);
        k_softsum<<<640, 256, 0, stream>>>(att_c, enc_c, length_sent,
                                           sent_pad + 512, sent_pad, 64, 640);
        // ---- sentence-phase prep (into xp region) ----
        p_whh_swz<<<96, 256, 0, stream>>>(sWhhF, swzSF, mode);
        p_whh_swz<<<96, 256, 0, stream>>>(sWhhB, swzSB, mode);
        p_cvt<<<256, 256, 0, stream>>>(sWihF, swih, 768 * 512, mode);
        p_cvt<<<256, 256, 0, stream>>>(sWihB, swih + (size_t)768 * 512, 768 * 512, mode);
        p_cvt_h<<<128, 256, 0, stream>>>(sLinW, slin_h, 512 * 512, mode);
        // ---- sentence level ----
        k_sent_xp<<<640, 256, 0, stream>>>(sent_order, sent_pad, swih, sBihF, sBihB,
                                           each_sent, xp_s, mode);
        k_gru<<<2, 512, 0, stream>>>(xp_s, swzSF, swzSB, sBhhF, sBhhB,
                                     length_doc, enc_s, 40, 16, mode);
        k_att<<<10, 256, 0, stream>>>(enc_s, slin_h, sLinB, sAttw, att_s, mode);
        k_softsum<<<16, 256, 0, stream>>>(att_s, enc_s, length_doc, doc_embs, nullptr, 40, 16);
        // ---- scoring ----
        k_final<<<512, 256, 0, stream>>>(men_sent_idx, can_ent_idx, cand_mask, embed_ent,
                                         each_sent, doc_embs, mlpW, mlpB, d_out, mode);
        return;
    }

    // ======== chunked fallback (round-2 known-good layout) ========
    const size_t HEAD =
        256 + 4 * (size_t)196608 * 2 +
        (size_t)1536 * 512 * 2 + (size_t)512 * 512 * 2 +
        (size_t)1536 * 512 * 2 + (size_t)512 * 512 * 2 +
        (size_t)328192 * 4;
    const size_t SENT_REGION = 1310720 + 1966080 + 655360 + 2816 + 32768;
    auto need = [&](int nbq, int e) -> size_t {
        size_t word = (size_t)nbq * (196608 + 65536 + 256);
        size_t region = word > SENT_REGION ? word : SENT_REGION;
        return HEAD + region + (e ? N_EMB * 2 : 0) + (1u << 20);
    };
    int emb_cvt = 1, nb = 320;
    {
        const int ladder[5] = {320, 160, 80, 40, 16};
        bool found = false;
        for (int i = 0; i < 5 && !found; ++i)
            for (int e = 1; e >= 0 && !found; --e)
                if (need(ladder[i], e) <= ws_size) { emb_cvt = e; nb = ladder[i]; found = true; }
    }

    size_t off = 0;
    auto take = [&](size_t bytes) -> void* {
        void* p = base + off; off += (bytes + 255) & ~(size_t)255; return p;
    };
    int* mode = (int*)take(256);
    unsigned short* swzWF = (unsigned short*)take((size_t)196608 * 2);
    unsigned short* swzWB = (unsigned short*)take((size_t)196608 * 2);
    unsigned short* swzSF = (unsigned short*)take((size_t)196608 * 2);
    unsigned short* swzSB = (unsigned short*)take((size_t)196608 * 2);
    unsigned short* wih_w = (unsigned short*)take((size_t)1536 * 512 * 2);
    unsigned short* lin_h = (unsigned short*)take((size_t)512 * 512 * 2);
    unsigned short* swih  = (unsigned short*)take((size_t)1536 * 512 * 2);
    unsigned short* slin_h= (unsigned short*)take((size_t)512 * 512 * 2);
    float* sent_pad  = (float*)take((size_t)328192 * 4);

    size_t word_bytes = (size_t)nb * (196608 + 65536 + 256);
    size_t region_bytes = word_bytes > SENT_REGION ? word_bytes : SENT_REGION;
    char* region = (char*)take(region_bytes);
    unsigned short* xp_c  = (unsigned short*)region;
    unsigned short* enc_c = (unsigned short*)(region + (size_t)nb * 196608);
    float* att_c          = (float*)(region + (size_t)nb * 196608 + (size_t)nb * 65536);
    float* each_sent      = (float*)region;
    unsigned short* xp_s  = (unsigned short*)(region + 1310720);
    unsigned short* enc_s = (unsigned short*)(region + 1310720 + 1966080);
    float* att_s          = (float*)(region + 1310720 + 1966080 + 655360);
    float* doc_embs       = (float*)(region + 1310720 + 1966080 + 655360 + 2816);

    unsigned short* emb_bf = emb_cvt ? (unsigned short*)take(N_EMB * 2) : nullptr;

    k_probe<<<1, 64, 0, stream>>>((const unsigned short*)wWhhF, mode);
    p_whh_swz<<<96, 256, 0, stream>>>(wWhhF, swzWF, mode);
    p_whh_swz<<<96, 256, 0, stream>>>(wWhhB, swzWB, mode);
    p_whh_swz<<<96, 256, 0, stream>>>(sWhhF, swzSF, mode);
    p_whh_swz<<<96, 256, 0, stream>>>(sWhhB, swzSB, mode);
    p_cvt<<<256, 256, 0, stream>>>(wWihF, wih_w, 768 * 512, mode);
    p_cvt<<<256, 256, 0, stream>>>(wWihB, wih_w + (size_t)768 * 512, 768 * 512, mode);
    p_cvt_h<<<256, 256, 0, stream>>>(wLinW, lin_h, 512 * 512, mode);
    p_cvt<<<256, 256, 0, stream>>>(sWihF, swih, 768 * 512, mode);
    p_cvt<<<256, 256, 0, stream>>>(sWihB, swih + (size_t)768 * 512, 768 * 512, mode);
    p_cvt_h<<<256, 256, 0, stream>>>(sLinW, slin_h, 512 * 512, mode);
    if (emb_cvt) p_cvt<<<2048, 256, 0, stream>>>(embed_doc, emb_bf, (int)N_EMB, mode);

    const void* embA = emb_cvt ? (const void*)emb_bf : embed_doc;
    const int* amode = emb_cvt ? (mode + 1) : mode;

    for (int b0 = 0; b0 < 640; b0 += nb) {
        k_xp_word<<<dim3(nb, 6), 256, 0, stream>>>(embA, batch_doc, wih_w,
                                                   wBihF, wBihB, xp_c, b0, nb, amode, mode);
        k_gru<<<2 * (nb / 16), 512, 0, stream>>>(xp_c, swzWF, swzWB, wBhhF, wBhhB,
                                                 length_sent + b0, enc_c, 64, nb, mode);
        k_att<<<nb, 256, 0, stream>>>(enc_c, lin_h, wLinB, wAttw, att_c, mode);
        k_softsum<<<nb, 256, 0, stream>>>(att_c, enc_c, length_sent + b0,
                                          sent_pad + (size_t)(1 + b0) * 512,
                                          (b0 == 0) ? sent_pad : nullptr, 64, nb);
    }
    k_sent_xp<<<640, 256, 0, stream>>>(sent_order, sent_pad, swih, sBihF, sBihB,
                                       each_sent, xp_s, mode);
    k_gru<<<2, 512, 0, stream>>>(xp_s, swzSF, swzSB, sBhhF, sBhhB,
                                 length_doc, enc_s, 40, 16, mode);
    k_att<<<10, 256, 0, stream>>>(enc_s, slin_h, sLinB, sAttw, att_s, mode);
    k_softsum<<<16, 256, 0, stream>>>(att_s, enc_s, length_doc, doc_embs, nullptr, 40, 16);
    k_final<<<512, 256, 0, stream>>>(men_sent_idx, can_ent_idx, cand_mask, embed_ent,
                                     each_sent, doc_embs, mlpW, mlpB, d_out, mode);
}